// Round 1
// baseline (245.785 us; speedup 1.0000x reference)
//
#include <hip/hip_runtime.h>

// Laplace transform forward: out[n,i,f] = e[i]*out[n-1,i,f] + decay[i]*inp[n,f]
// T=2048, F=256, N_S=108. float32 in / float32 out.
//
// R3: exact time-parallel decomposition (3-phase chunk scan), replacing the
// R2 approximate warm-up (48 redundant iters/wave, 43% of wave runtime, and
// only 3.4 blocks/CU). The diagonal recurrence over a 32-step chunk composes:
//   t_{end(b)} = e^32 * t_{end(b-1)} + L_b   (L_b = local scan from zero)
// Phase A: locals L_b for all 64 chunks (1728 blocks, ~3us, 7MB ws writes)
// Phase B: sequential combine over b (27 blocks, ~2us) -> exact entering
//          states in-place in ws
// Phase C: main loop, CHUNK=32, no warm-up, 1728 blocks = 6.75 blocks/CU
//          (vs 3.375 before), nontemporal 226.5MB output stream.
// Kernel floor: 226.5MB / 6.3TB/s ~= 36us. R2 kernel was ~92us (2.4TB/s eff).

#define T_LEN 2048
#define F_DIM 256
#define NS    108      // NTAU + 2*K = 100 + 8
#define KPAD  4
#define CH    32
#define NB    (T_LEN / CH)   // 64 chunks

typedef float f32x4 __attribute__((ext_vector_type(4)));

__device__ __forceinline__ void laplace_consts(int i, float& s, float& e, float& decay) {
    // per-taustar constants (~2% of a wave's setup; powf/expf fine)
    const float c   = powf(20.0f, 1.0f / 99.0f) - 1.0f;
    const float tau = powf(1.0f + c, (float)(i - KPAD));
    s     = 4.0f / tau;
    e     = expf(-s);
    decay = (1.0f - e) / s;
}

// ws slot for (chunk b, taustar i, f4-group lane): float4
__device__ __forceinline__ size_t ws_idx(int b, int i, int lane) {
    return (((size_t)b * NS + i) * 64 + lane) * 4;
}

// Phase A: local 32-step scan from zero state -> L_b
__global__ __launch_bounds__(256) void laplace_local(
    const float* __restrict__ inp,   // (T, F)
    float* __restrict__ ws)          // (NB, NS, 64) float4
{
    const int lane = threadIdx.x & 63;
    const int i    = blockIdx.y * 4 + (threadIdx.x >> 6);
    const int b    = blockIdx.x;

    float s, e, decay;
    laplace_consts(i, s, e, decay);

    const float* ip = inp + lane * 4;
    float t0 = 0.f, t1 = 0.f, t2 = 0.f, t3 = 0.f;

    const int n0 = b * CH;
    #pragma unroll 8
    for (int n = n0; n < n0 + CH; ++n) {
        f32x4 x = *(const f32x4*)(ip + (size_t)n * F_DIM);
        t0 = fmaf(e, t0, decay * x.x);
        t1 = fmaf(e, t1, decay * x.y);
        t2 = fmaf(e, t2, decay * x.z);
        t3 = fmaf(e, t3, decay * x.w);
    }
    f32x4 r; r.x = t0; r.y = t1; r.z = t2; r.w = t3;
    *(f32x4*)(ws + ws_idx(b, i, lane)) = r;
}

// Phase B: in-place combine. After this, ws[b] holds the EXACT state
// entering chunk b: S_0 = 0; S_{b+1} = g*S_b + L_b, g = e^CH.
__global__ __launch_bounds__(256) void laplace_combine(
    float* __restrict__ ws)
{
    const int lane = threadIdx.x & 63;
    const int i    = blockIdx.x * 4 + (threadIdx.x >> 6);

    float s, e, decay;
    laplace_consts(i, s, e, decay);
    const float g = expf(-s * (float)CH);   // e^CH

    float S0 = 0.f, S1 = 0.f, S2 = 0.f, S3 = 0.f;
    #pragma unroll 8
    for (int b = 0; b < NB; ++b) {
        f32x4* p = (f32x4*)(ws + ws_idx(b, i, lane));
        f32x4 L = *p;            // read local before overwrite (same thread)
        f32x4 S; S.x = S0; S.y = S1; S.z = S2; S.w = S3;
        *p = S;                  // entering state for chunk b
        S0 = fmaf(g, S0, L.x);
        S1 = fmaf(g, S1, L.y);
        S2 = fmaf(g, S2, L.z);
        S3 = fmaf(g, S3, L.w);
    }
}

// Phase C: exact-state main loop, no warm-up.
__global__ __launch_bounds__(256) void laplace_main(
    const float* __restrict__ inp,
    const float* __restrict__ ws,
    float* __restrict__ out)         // (T, NS, F)
{
    const int lane = threadIdx.x & 63;
    const int f0   = lane * 4;
    const int i    = blockIdx.x * 4 + (threadIdx.x >> 6);  // x = i-group (27)
    const int b    = blockIdx.y;                           // y = chunk (64)
    const int n0   = b * CH;

    float s, e, decay;
    laplace_consts(i, s, e, decay);

    f32x4 S = *(const f32x4*)(ws + ws_idx(b, i, lane));
    float t0 = S.x, t1 = S.y, t2 = S.z, t3 = S.w;

    const float* ip = inp + f0;
    float* op = out + (size_t)i * F_DIM + f0;

    #pragma unroll 8
    for (int n = n0; n < n0 + CH; ++n) {
        f32x4 x = *(const f32x4*)(ip + (size_t)n * F_DIM);
        t0 = fmaf(e, t0, decay * x.x);
        t1 = fmaf(e, t1, decay * x.y);
        t2 = fmaf(e, t2, decay * x.z);
        t3 = fmaf(e, t3, decay * x.w);
        f32x4 r; r.x = t0; r.y = t1; r.z = t2; r.w = t3;
        __builtin_nontemporal_store(r, (f32x4*)(op + (size_t)n * (NS * F_DIM)));
    }
}

// Fallback (R2 kernel): approximate warm-up, used only if ws is too small.
#define CHUNK_FB 64
#define WARM_FB  48
__global__ __launch_bounds__(256) void laplace_kernel_fb(
    const float* __restrict__ inp,
    float* __restrict__ out)
{
    const int tid  = threadIdx.x;
    const int lane = tid & 63;
    const int f0   = lane * 4;
    const int i    = blockIdx.y * 4 + (tid >> 6);
    const int n0   = blockIdx.x * CHUNK_FB;

    float s, e, decay;
    laplace_consts(i, s, e, decay);

    const float* ip = inp + f0;
    float t0 = 0.f, t1 = 0.f, t2 = 0.f, t3 = 0.f;

    int nstart = n0 - WARM_FB;
    if (nstart < 0) nstart = 0;
    #pragma unroll 4
    for (int n = nstart; n < n0; ++n) {
        f32x4 x = *(const f32x4*)(ip + (size_t)n * F_DIM);
        t0 = fmaf(e, t0, decay * x.x);
        t1 = fmaf(e, t1, decay * x.y);
        t2 = fmaf(e, t2, decay * x.z);
        t3 = fmaf(e, t3, decay * x.w);
    }
    float* op = out + (size_t)i * F_DIM + f0;
    #pragma unroll 4
    for (int n = n0; n < n0 + CHUNK_FB; ++n) {
        f32x4 x = *(const f32x4*)(ip + (size_t)n * F_DIM);
        t0 = fmaf(e, t0, decay * x.x);
        t1 = fmaf(e, t1, decay * x.y);
        t2 = fmaf(e, t2, decay * x.z);
        t3 = fmaf(e, t3, decay * x.w);
        f32x4 r; r.x = t0; r.y = t1; r.z = t2; r.w = t3;
        __builtin_nontemporal_store(r, (f32x4*)(op + (size_t)n * (NS * F_DIM)));
    }
}

extern "C" void kernel_launch(void* const* d_in, const int* in_sizes, int n_in,
                              void* d_out, int out_size, void* d_ws, size_t ws_size,
                              hipStream_t stream) {
    const float* inp = (const float*)d_in[0];
    float* out = (float*)d_out;

    const size_t ws_need = (size_t)NB * NS * 64 * 4 * sizeof(float);  // 7,077,888 B

    if (d_ws != nullptr && ws_size >= ws_need) {
        float* ws = (float*)d_ws;
        // A: locals (1728 blocks), B: combine (27 blocks), C: main (1728 blocks)
        laplace_local  <<<dim3(NB, NS / 4), 256, 0, stream>>>(inp, ws);
        laplace_combine<<<dim3(NS / 4),     256, 0, stream>>>(ws);
        laplace_main   <<<dim3(NS / 4, NB), 256, 0, stream>>>(inp, ws, out);
    } else {
        laplace_kernel_fb<<<dim3(T_LEN / CHUNK_FB, NS / 4), 256, 0, stream>>>(inp, out);
    }
}

// Round 2
// 235.074 us; speedup vs baseline: 1.0456x; 1.0456x over previous
//
#include <hip/hip_runtime.h>

// Laplace transform forward: out[n,i,f] = e[i]*out[n-1,i,f] + decay[i]*inp[n,f]
// T=2048, F=256, N_S=108. float32 in / float32 out.
//
// R4: R3's exact 3-phase chunk scan, with REGULAR stores instead of
// nontemporal. R3 post-mortem: removing warm-up + doubling TLP changed
// nothing (kernel ~100us, writes ~2.5 TB/s eff), while the harness fill
// does 6.3 TB/s of plain stores on the same buffer. Remaining suspect:
// __builtin_nontemporal_store bypasses L2 write-combining / L3 (output is
// 216MB vs 256MB Infinity Cache). Input rereads (2MB) stay L2-resident
// regardless, so NT protected nothing.
//
// Phase A: locals L_b for all 64 chunks (1728 blocks, ~5us, 7MB ws writes)
// Phase B: sequential combine over b (27 blocks, ~2us) -> exact entering
//          states in-place in ws
// Phase C: main loop, CHUNK=32, no warm-up, 1728 blocks co-resident,
//          226.5MB output stream via plain float4 stores.
// Kernel floor: 226.5MB / 6.3TB/s ~= 36us.

#define T_LEN 2048
#define F_DIM 256
#define NS    108      // NTAU + 2*K = 100 + 8
#define KPAD  4
#define CH    32
#define NB    (T_LEN / CH)   // 64 chunks

typedef float f32x4 __attribute__((ext_vector_type(4)));

__device__ __forceinline__ void laplace_consts(int i, float& s, float& e, float& decay) {
    // per-taustar constants (~2% of a wave's setup; powf/expf fine)
    const float c   = powf(20.0f, 1.0f / 99.0f) - 1.0f;
    const float tau = powf(1.0f + c, (float)(i - KPAD));
    s     = 4.0f / tau;
    e     = expf(-s);
    decay = (1.0f - e) / s;
}

// ws slot for (chunk b, taustar i, f4-group lane): float4
__device__ __forceinline__ size_t ws_idx(int b, int i, int lane) {
    return (((size_t)b * NS + i) * 64 + lane) * 4;
}

// Phase A: local 32-step scan from zero state -> L_b
__global__ __launch_bounds__(256) void laplace_local(
    const float* __restrict__ inp,   // (T, F)
    float* __restrict__ ws)          // (NB, NS, 64) float4
{
    const int lane = threadIdx.x & 63;
    const int i    = blockIdx.y * 4 + (threadIdx.x >> 6);
    const int b    = blockIdx.x;

    float s, e, decay;
    laplace_consts(i, s, e, decay);

    const float* ip = inp + lane * 4;
    float t0 = 0.f, t1 = 0.f, t2 = 0.f, t3 = 0.f;

    const int n0 = b * CH;
    #pragma unroll 8
    for (int n = n0; n < n0 + CH; ++n) {
        f32x4 x = *(const f32x4*)(ip + (size_t)n * F_DIM);
        t0 = fmaf(e, t0, decay * x.x);
        t1 = fmaf(e, t1, decay * x.y);
        t2 = fmaf(e, t2, decay * x.z);
        t3 = fmaf(e, t3, decay * x.w);
    }
    f32x4 r; r.x = t0; r.y = t1; r.z = t2; r.w = t3;
    *(f32x4*)(ws + ws_idx(b, i, lane)) = r;
}

// Phase B: in-place combine. After this, ws[b] holds the EXACT state
// entering chunk b: S_0 = 0; S_{b+1} = g*S_b + L_b, g = e^CH.
__global__ __launch_bounds__(256) void laplace_combine(
    float* __restrict__ ws)
{
    const int lane = threadIdx.x & 63;
    const int i    = blockIdx.x * 4 + (threadIdx.x >> 6);

    float s, e, decay;
    laplace_consts(i, s, e, decay);
    const float g = expf(-s * (float)CH);   // e^CH

    float S0 = 0.f, S1 = 0.f, S2 = 0.f, S3 = 0.f;
    #pragma unroll 8
    for (int b = 0; b < NB; ++b) {
        f32x4* p = (f32x4*)(ws + ws_idx(b, i, lane));
        f32x4 L = *p;            // read local before overwrite (same thread)
        f32x4 S; S.x = S0; S.y = S1; S.z = S2; S.w = S3;
        *p = S;                  // entering state for chunk b
        S0 = fmaf(g, S0, L.x);
        S1 = fmaf(g, S1, L.y);
        S2 = fmaf(g, S2, L.z);
        S3 = fmaf(g, S3, L.w);
    }
}

// Phase C: exact-state main loop, no warm-up. Plain stores (R4 change).
__global__ __launch_bounds__(256) void laplace_main(
    const float* __restrict__ inp,
    const float* __restrict__ ws,
    float* __restrict__ out)         // (T, NS, F)
{
    const int lane = threadIdx.x & 63;
    const int f0   = lane * 4;
    const int i    = blockIdx.x * 4 + (threadIdx.x >> 6);  // x = i-group (27)
    const int b    = blockIdx.y;                           // y = chunk (64)
    const int n0   = b * CH;

    float s, e, decay;
    laplace_consts(i, s, e, decay);

    f32x4 S = *(const f32x4*)(ws + ws_idx(b, i, lane));
    float t0 = S.x, t1 = S.y, t2 = S.z, t3 = S.w;

    const float* ip = inp + f0;
    float* op = out + (size_t)i * F_DIM + f0;

    #pragma unroll 8
    for (int n = n0; n < n0 + CH; ++n) {
        f32x4 x = *(const f32x4*)(ip + (size_t)n * F_DIM);
        t0 = fmaf(e, t0, decay * x.x);
        t1 = fmaf(e, t1, decay * x.y);
        t2 = fmaf(e, t2, decay * x.z);
        t3 = fmaf(e, t3, decay * x.w);
        f32x4 r; r.x = t0; r.y = t1; r.z = t2; r.w = t3;
        *(f32x4*)(op + (size_t)n * (NS * F_DIM)) = r;   // regular store (was NT)
    }
}

// Fallback (approximate warm-up), used only if ws is too small.
#define CHUNK_FB 64
#define WARM_FB  48
__global__ __launch_bounds__(256) void laplace_kernel_fb(
    const float* __restrict__ inp,
    float* __restrict__ out)
{
    const int tid  = threadIdx.x;
    const int lane = tid & 63;
    const int f0   = lane * 4;
    const int i    = blockIdx.y * 4 + (tid >> 6);
    const int n0   = blockIdx.x * CHUNK_FB;

    float s, e, decay;
    laplace_consts(i, s, e, decay);

    const float* ip = inp + f0;
    float t0 = 0.f, t1 = 0.f, t2 = 0.f, t3 = 0.f;

    int nstart = n0 - WARM_FB;
    if (nstart < 0) nstart = 0;
    #pragma unroll 4
    for (int n = nstart; n < n0; ++n) {
        f32x4 x = *(const f32x4*)(ip + (size_t)n * F_DIM);
        t0 = fmaf(e, t0, decay * x.x);
        t1 = fmaf(e, t1, decay * x.y);
        t2 = fmaf(e, t2, decay * x.z);
        t3 = fmaf(e, t3, decay * x.w);
    }
    float* op = out + (size_t)i * F_DIM + f0;
    #pragma unroll 4
    for (int n = n0; n < n0 + CHUNK_FB; ++n) {
        f32x4 x = *(const f32x4*)(ip + (size_t)n * F_DIM);
        t0 = fmaf(e, t0, decay * x.x);
        t1 = fmaf(e, t1, decay * x.y);
        t2 = fmaf(e, t2, decay * x.z);
        t3 = fmaf(e, t3, decay * x.w);
        f32x4 r; r.x = t0; r.y = t1; r.z = t2; r.w = t3;
        *(f32x4*)(op + (size_t)n * (NS * F_DIM)) = r;
    }
}

extern "C" void kernel_launch(void* const* d_in, const int* in_sizes, int n_in,
                              void* d_out, int out_size, void* d_ws, size_t ws_size,
                              hipStream_t stream) {
    const float* inp = (const float*)d_in[0];
    float* out = (float*)d_out;

    const size_t ws_need = (size_t)NB * NS * 64 * 4 * sizeof(float);  // 7,077,888 B

    if (d_ws != nullptr && ws_size >= ws_need) {
        float* ws = (float*)d_ws;
        // A: locals (1728 blocks), B: combine (27 blocks), C: main (1728 blocks)
        laplace_local  <<<dim3(NB, NS / 4), 256, 0, stream>>>(inp, ws);
        laplace_combine<<<dim3(NS / 4),     256, 0, stream>>>(ws);
        laplace_main   <<<dim3(NS / 4, NB), 256, 0, stream>>>(inp, ws, out);
    } else {
        laplace_kernel_fb<<<dim3(T_LEN / CHUNK_FB, NS / 4), 256, 0, stream>>>(inp, out);
    }
}